// Round 1
// baseline (569.208 us; speedup 1.0000x reference)
//
#include <hip/hip_runtime.h>

#define N_RES 768
#define C_M 256
#define C_Z 128
#define NO_BINS 15

// ---------------------------------------------------------------------------
// Kernel 1: m_update = LayerNorm(m) * g_m + be_m     [768 rows x 256 ch]
// One wave (64 lanes) per row, float4 per lane.
// ---------------------------------------------------------------------------
__global__ __launch_bounds__(64) void ln_m_kernel(const float* __restrict__ m,
                                                  const float* __restrict__ g,
                                                  const float* __restrict__ b,
                                                  float* __restrict__ out) {
    const int row  = blockIdx.x;
    const int lane = threadIdx.x;           // 0..63
    const float4 v = ((const float4*)(m + row * C_M))[lane];
    float s  = v.x + v.y + v.z + v.w;
    float ss = v.x * v.x + v.y * v.y + v.z * v.z + v.w * v.w;
#pragma unroll
    for (int off = 32; off >= 1; off >>= 1) {
        s  += __shfl_xor(s,  off);
        ss += __shfl_xor(ss, off);
    }
    const float mu  = s * (1.0f / C_M);
    const float var = ss * (1.0f / C_M) - mu * mu;
    const float rs  = rsqrtf(var + 1e-5f);
    const float4 gv = ((const float4*)g)[lane];
    const float4 bv = ((const float4*)b)[lane];
    float4 o;
    o.x = (v.x - mu) * rs * gv.x + bv.x;
    o.y = (v.y - mu) * rs * gv.y + bv.y;
    o.z = (v.z - mu) * rs * gv.z + bv.z;
    o.w = (v.w - mu) * rs * gv.w + bv.w;
    ((float4*)(out + row * C_M))[lane] = o;
}

// ---------------------------------------------------------------------------
// Kernel 2: z_update = distogram_embed(d2) + LayerNorm(z) * g_z + be_z + b_lin
// 768*768 = 589824 rows of 128 channels. 256 threads/block; each 32-lane
// half-wave owns one row with float4 per lane (16 B coalescing sweet spot).
// Shuffle reduction uses xor masks 1..16 only -> stays within each half.
// ---------------------------------------------------------------------------
__global__ __launch_bounds__(256) void z_fused_kernel(const float* __restrict__ z,
                                                      const float* __restrict__ x,
                                                      const float* __restrict__ w_lin,
                                                      const float* __restrict__ b_lin,
                                                      const float* __restrict__ g_z,
                                                      const float* __restrict__ be_z,
                                                      float* __restrict__ out) {
    __shared__ float wt[NO_BINS * C_Z];   // transposed w_lin: wt[b*128 + c]
    __shared__ float gz_s[C_Z];
    __shared__ float bias_s[C_Z];         // be_z + b_lin

    const int tid = threadIdx.x;
    for (int idx = tid; idx < NO_BINS * C_Z; idx += 256) {
        const int c = idx / NO_BINS;
        const int b = idx - c * NO_BINS;
        wt[b * C_Z + c] = w_lin[idx];     // w_lin is [C_Z, NO_BINS] row-major
    }
    if (tid < C_Z) {
        gz_s[tid]   = g_z[tid];
        bias_s[tid] = be_z[tid] + b_lin[tid];
    }
    __syncthreads();

    const int half = tid >> 5;            // 0..7 : which row within block
    const int hl   = tid & 31;            // lane within half-wave
    const int row  = blockIdx.x * 8 + half;   // < 589824
    const int i    = row / N_RES;
    const int j    = row - i * N_RES;

    // squared distance, exact IEEE order (no fma contraction) to match ref binning
    const float dx = x[i * 3 + 0] - x[j * 3 + 0];
    const float dy = x[i * 3 + 1] - x[j * 3 + 1];
    const float dz = x[i * 3 + 2] - x[j * 3 + 2];
    const float d2 = __fadd_rn(__fadd_rn(__fmul_rn(dx, dx), __fmul_rn(dy, dy)),
                               __fmul_rn(dz, dz));

    // one-hot bin: b active iff sq_bins[b] < d2 < upper[b]; at most one active
    int bin = -1;
#pragma unroll
    for (int b = 0; b < NO_BINS; b++) {
        const float lov = 3.25f + 1.25f * (float)b;
        const float hiv = 3.25f + 1.25f * (float)(b + 1);
        const float lo  = lov * lov;                       // constant-folded fp32
        const float hi  = (b < NO_BINS - 1) ? hiv * hiv : 1e8f;
        if (d2 > lo && d2 < hi) bin = b;
    }

    // layernorm over this row's 128 channels
    const float4 v = ((const float4*)(z + (size_t)row * C_Z))[hl];
    float s  = v.x + v.y + v.z + v.w;
    float ss = v.x * v.x + v.y * v.y + v.z * v.z + v.w * v.w;
#pragma unroll
    for (int off = 16; off >= 1; off >>= 1) {   // stays within 32-lane half
        s  += __shfl_xor(s,  off);
        ss += __shfl_xor(ss, off);
    }
    const float mu  = s * (1.0f / C_Z);
    const float var = ss * (1.0f / C_Z) - mu * mu;
    const float rs  = rsqrtf(var + 1e-5f);

    const float4 gv = ((const float4*)gz_s)[hl];
    const float4 bv = ((const float4*)bias_s)[hl];
    float4 wv = make_float4(0.f, 0.f, 0.f, 0.f);
    if (bin >= 0) wv = ((const float4*)(wt + bin * C_Z))[hl];

    float4 o;
    o.x = (v.x - mu) * rs * gv.x + bv.x + wv.x;
    o.y = (v.y - mu) * rs * gv.y + bv.y + wv.y;
    o.z = (v.z - mu) * rs * gv.z + bv.z + wv.z;
    o.w = (v.w - mu) * rs * gv.w + bv.w + wv.w;
    ((float4*)(out + (size_t)row * C_Z))[hl] = o;
}

extern "C" void kernel_launch(void* const* d_in, const int* in_sizes, int n_in,
                              void* d_out, int out_size, void* d_ws, size_t ws_size,
                              hipStream_t stream) {
    const float* m     = (const float*)d_in[0];
    const float* z     = (const float*)d_in[1];
    const float* x     = (const float*)d_in[2];
    const float* w_lin = (const float*)d_in[3];
    const float* b_lin = (const float*)d_in[4];
    const float* g_m   = (const float*)d_in[5];
    const float* be_m  = (const float*)d_in[6];
    const float* g_z   = (const float*)d_in[7];
    const float* be_z  = (const float*)d_in[8];

    float* out   = (float*)d_out;
    float* out_m = out;                       // [768*256]
    float* out_z = out + N_RES * C_M;         // [768*768*128]

    ln_m_kernel<<<N_RES, 64, 0, stream>>>(m, g_m, be_m, out_m);

    const int n_rows = N_RES * N_RES;         // 589824
    z_fused_kernel<<<n_rows / 8, 256, 0, stream>>>(z, x, w_lin, b_lin, g_z, be_z, out_z);
}

// Round 2
// 497.881 us; speedup vs baseline: 1.1433x; 1.1433x over previous
//
#include <hip/hip_runtime.h>

#define N_RES 768
#define C_M 256
#define C_Z 128
#define NO_BINS 15

// ---------------------------------------------------------------------------
// Prep kernel (1 block, trivial): build into d_ws
//   wt[b*128 + c]  = w_lin[c*15 + b]   (transposed linear weight, 1920 floats)
//   bias[c]        = be_z[c] + b_lin[c]  (128 floats, at offset 1920)
// ---------------------------------------------------------------------------
__global__ __launch_bounds__(256) void prep_kernel(const float* __restrict__ w_lin,
                                                   const float* __restrict__ b_lin,
                                                   const float* __restrict__ be_z,
                                                   float* __restrict__ ws) {
    const int tid = threadIdx.x;
    for (int idx = tid; idx < NO_BINS * C_Z; idx += 256) {
        const int c = idx / NO_BINS;
        const int b = idx - c * NO_BINS;
        ws[b * C_Z + c] = w_lin[idx];
    }
    if (tid < C_Z) {
        ws[NO_BINS * C_Z + tid] = be_z[tid] + b_lin[tid];
    }
}

// ---------------------------------------------------------------------------
// Kernel 1: m_update = LayerNorm(m) * g_m + be_m     [768 rows x 256 ch]
// One wave (64 lanes) per row, float4 per lane.
// ---------------------------------------------------------------------------
__global__ __launch_bounds__(64) void ln_m_kernel(const float* __restrict__ m,
                                                  const float* __restrict__ g,
                                                  const float* __restrict__ b,
                                                  float* __restrict__ out) {
    const int row  = blockIdx.x;
    const int lane = threadIdx.x;           // 0..63
    const float4 v = ((const float4*)(m + row * C_M))[lane];
    float s  = v.x + v.y + v.z + v.w;
    float ss = v.x * v.x + v.y * v.y + v.z * v.z + v.w * v.w;
#pragma unroll
    for (int off = 32; off >= 1; off >>= 1) {
        s  += __shfl_xor(s,  off);
        ss += __shfl_xor(ss, off);
    }
    const float mu  = s * (1.0f / C_M);
    const float var = ss * (1.0f / C_M) - mu * mu;
    const float rs  = rsqrtf(var + 1e-5f);
    const float4 gv = ((const float4*)g)[lane];
    const float4 bv = ((const float4*)b)[lane];
    float4 o;
    o.x = (v.x - mu) * rs * gv.x + bv.x;
    o.y = (v.y - mu) * rs * gv.y + bv.y;
    o.z = (v.z - mu) * rs * gv.z + bv.z;
    o.w = (v.w - mu) * rs * gv.w + bv.w;
    ((float4*)(out + row * C_M))[lane] = o;
}

// ---------------------------------------------------------------------------
// Kernel 2: z_update = distogram_embed(d2) + LayerNorm(z) * g_z + be_z + b_lin
// 768*768 = 589824 rows of 128 channels. 256 threads/block; each 32-lane
// half-wave owns one row with float4 per lane. NO __shared__ -> no barrier,
// no LDS bank conflicts (only the ds_swizzle shuffles remain).
// wt/bias come from d_ws (7.7 KB, L1/L2-resident); g_z read directly.
// ---------------------------------------------------------------------------
__global__ __launch_bounds__(256) void z_fused_kernel(const float* __restrict__ z,
                                                      const float* __restrict__ x,
                                                      const float* __restrict__ ws,
                                                      const float* __restrict__ g_z,
                                                      float* __restrict__ out) {
    const int tid  = threadIdx.x;
    const int half = tid >> 5;            // 0..7 : which row within block
    const int hl   = tid & 31;            // lane within half-wave
    const int row  = blockIdx.x * 8 + half;   // < 589824
    const int i    = row / N_RES;
    const int j    = row - i * N_RES;

    // squared distance, exact IEEE order (no fma contraction) to match ref binning
    const float dx = x[i * 3 + 0] - x[j * 3 + 0];
    const float dy = x[i * 3 + 1] - x[j * 3 + 1];
    const float dz = x[i * 3 + 2] - x[j * 3 + 2];
    const float d2 = __fadd_rn(__fadd_rn(__fmul_rn(dx, dx), __fmul_rn(dy, dy)),
                               __fmul_rn(dz, dz));

    // one-hot bin: b active iff sq_bins[b] < d2 < upper[b]; at most one active
    int bin = -1;
#pragma unroll
    for (int b = 0; b < NO_BINS; b++) {
        const float lov = 3.25f + 1.25f * (float)b;
        const float hiv = 3.25f + 1.25f * (float)(b + 1);
        const float lo  = lov * lov;                       // constant-folded fp32
        const float hi  = (b < NO_BINS - 1) ? hiv * hiv : 1e8f;
        if (d2 > lo && d2 < hi) bin = b;
    }

    // layernorm over this row's 128 channels
    const float4 v = ((const float4*)(z + (size_t)row * C_Z))[hl];
    float s  = v.x + v.y + v.z + v.w;
    float ss = v.x * v.x + v.y * v.y + v.z * v.z + v.w * v.w;
#pragma unroll
    for (int off = 16; off >= 1; off >>= 1) {   // stays within 32-lane half
        s  += __shfl_xor(s,  off);
        ss += __shfl_xor(ss, off);
    }
    const float mu  = s * (1.0f / C_Z);
    const float var = ss * (1.0f / C_Z) - mu * mu;
    const float rs  = rsqrtf(var + 1e-5f);

    const float4 gv = ((const float4*)g_z)[hl];
    const float4 bv = ((const float4*)(ws + NO_BINS * C_Z))[hl];
    float4 wv = make_float4(0.f, 0.f, 0.f, 0.f);
    if (bin >= 0) wv = ((const float4*)(ws + bin * C_Z))[hl];

    float4 o;
    o.x = (v.x - mu) * rs * gv.x + bv.x + wv.x;
    o.y = (v.y - mu) * rs * gv.y + bv.y + wv.y;
    o.z = (v.z - mu) * rs * gv.z + bv.z + wv.z;
    o.w = (v.w - mu) * rs * gv.w + bv.w + wv.w;
    ((float4*)(out + (size_t)row * C_Z))[hl] = o;
}

extern "C" void kernel_launch(void* const* d_in, const int* in_sizes, int n_in,
                              void* d_out, int out_size, void* d_ws, size_t ws_size,
                              hipStream_t stream) {
    const float* m     = (const float*)d_in[0];
    const float* z     = (const float*)d_in[1];
    const float* x     = (const float*)d_in[2];
    const float* w_lin = (const float*)d_in[3];
    const float* b_lin = (const float*)d_in[4];
    const float* g_m   = (const float*)d_in[5];
    const float* be_m  = (const float*)d_in[6];
    const float* g_z   = (const float*)d_in[7];
    const float* be_z  = (const float*)d_in[8];

    float* out   = (float*)d_out;
    float* out_m = out;                       // [768*256]
    float* out_z = out + N_RES * C_M;         // [768*768*128]
    float* ws    = (float*)d_ws;              // 1920 + 128 floats = 8192 B

    prep_kernel<<<1, 256, 0, stream>>>(w_lin, b_lin, be_z, ws);
    ln_m_kernel<<<N_RES, 64, 0, stream>>>(m, g_m, be_m, out_m);

    const int n_rows = N_RES * N_RES;         // 589824
    z_fused_kernel<<<n_rows / 8, 256, 0, stream>>>(z, x, ws, g_z, out_z);
}